// Round 19
// baseline (228.492 us; speedup 1.0000x reference)
//
#include <hip/hip_runtime.h>
#include <hip/hip_fp16.h>
#include <math.h>

#define N_NODES 50000
#define N_EDGES 800000
#define E2 (N_EDGES + N_NODES)   // 850000
#define HEADS 5
#define C1 32
#define F1 160
#define RSU 88                   // h1 row stride in ushorts (176 B): 80 fp8x2 + 5 as1 fp16 + pad
#define RSW 44                   // row stride in uints

// counting-sort CSR build (64-node buckets)
#define BSZ 64
#define NBK 782                  // 782*64 = 50048 >= N
#define NBL 128
#define CH  6641                 // 128*6641 >= E2
#define MTOT (NBK*NBL)           // 100096
#define MC  391                  // ceil(MTOT/256)
#define GRID_H1 (N_NODES/4)      // 12500 h1 blocks in k_init
#define CAP 1408                 // LDS staging cap per 64-node bucket

static constexpr size_t alignup(size_t x){ return (x + 255) & ~size_t(255); }
static constexpr size_t OFF_SCAL  = 0;                                           // 64 f
static constexpr size_t OFF_H     = alignup(OFF_SCAL + 64*4);                    // MTOT i
static constexpr size_t OFF_EAS   = alignup(OFF_H    + (size_t)MTOT*4);          // NBL f
static constexpr size_t OFF_PART  = alignup(OFF_EAS  + (size_t)NBL*4);           // MC i
static constexpr size_t OFF_PPREF = alignup(OFF_PART + (size_t)MC*4);            // MC i
static constexpr size_t OFF_BST   = alignup(OFF_PPREF+ (size_t)MC*4);            // NBK+1
static constexpr size_t OFF_OFFS  = alignup(OFF_BST  + (size_t)(NBK+1)*4);       // N+1
static constexpr size_t OFF_BPACK = alignup(OFF_OFFS + (size_t)(N_NODES+1)*4);   // E2 int2
static constexpr size_t OFF_EDG   = alignup(OFF_BPACK+ (size_t)E2*8);            // E2 u32
static constexpr size_t OFF_AD1P  = alignup(OFF_EDG  + (size_t)E2*4);            // N*8 f
static constexpr size_t OFF_G16   = alignup(OFF_AD1P + (size_t)N_NODES*8*4);     // N*16 half
static constexpr size_t OFF_AD2P  = alignup(OFF_G16  + (size_t)N_NODES*16*2);    // N*8 f
static constexpr size_t OFF_H1Q   = alignup(OFF_AD2P + (size_t)N_NODES*8*4);     // N*RSU ushort
static constexpr size_t OFF_X2H   = alignup(OFF_H1Q  + (size_t)N_NODES*RSU*2);   // N*160 half

typedef float vf2 __attribute__((ext_vector_type(2)));
__device__ __forceinline__ float4 fp8x4_to_f32(unsigned int r){
  vf2 lo = __builtin_amdgcn_cvt_pk_f32_fp8((int)r, false);
  vf2 hi = __builtin_amdgcn_cvt_pk_f32_fp8((int)r, true);
  return make_float4(lo.x, lo.y, hi.x, hi.y);
}

// ---- fused: layer-1 projection (fp8 h1 + fp16 as1 in one row) + coarse histogram ----
__global__ __launch_bounds__(320) void k_init(const float* __restrict__ x, const float* __restrict__ W1,
                       const float* __restrict__ as1w, const float* __restrict__ ad1w,
                       unsigned short* __restrict__ h1q, float* __restrict__ ad1p,
                       const int* __restrict__ dst, const float* __restrict__ ea,
                       int* __restrict__ H, float* __restrict__ easum){
  __shared__ float sW[5*F1];
  int t = threadIdx.x;
  if (blockIdx.x < GRID_H1){
    for (int k = t; k < 5*F1; k += 320) sW[k] = W1[k];
    __syncthreads();
    int nl = t / 80;
    int c  = t - nl*80;
    int n  = blockIdx.x*4 + nl;
    int c0 = 2*c;
    float hv0 = 0.f, hv1 = 0.f;
    #pragma unroll
    for (int f = 0; f < 5; f++){
      float xv = x[n*5 + f];
      hv0 += xv * sW[f*F1 + c0];
      hv1 += xv * sW[f*F1 + c0 + 1];
    }
    int pk = __builtin_amdgcn_cvt_pk_fp8_f32(hv0, hv1, 0, false);
    h1q[(size_t)n*RSU + c] = (unsigned short)(pk & 0xFFFF);
    float vs = hv0*as1w[c0] + hv1*as1w[c0+1];
    float vd = hv0*ad1w[c0] + hv1*ad1w[c0+1];
    #pragma unroll
    for (int m = 8; m >= 1; m >>= 1){
      vs += __shfl_xor(vs, m, 64);
      vd += __shfl_xor(vd, m, 64);
    }
    if ((c & 15) == 0){
      int h = c >> 4;
      h1q[(size_t)n*RSU + 80 + h] = __half_as_ushort(__float2half(vs));  // as1 in-row
      ad1p[n*8 + h] = vd;
    }
  } else {
    int* hist = (int*)sW;
    float* wsum = (float*)&hist[NBK + 1];
    for (int k = t; k < NBK; k += 320) hist[k] = 0;
    __syncthreads();
    int b = blockIdx.x - GRID_H1;
    int e0 = b*CH, e1 = min(e0 + CH, E2);
    float s = 0.f;
    for (int e = e0 + t; e < e1; e += 320){
      int d;
      if (e < N_EDGES){ d = dst[e]; s += ea[e]; }
      else d = e - N_EDGES;
      atomicAdd(&hist[d >> 6], 1);
    }
    #pragma unroll
    for (int m = 1; m < 64; m <<= 1) s += __shfl_xor(s, m, 64);
    if ((t & 63) == 0) wsum[t >> 6] = s;
    __syncthreads();
    for (int k = t; k < NBK; k += 320) H[(size_t)k*NBL + b] = hist[k];
    if (t == 0) easum[b] = wsum[0] + wsum[1] + wsum[2] + wsum[3] + wsum[4];
  }
}

// ---- parallel scan, stage 1 ----
__global__ void k_s1(const int* __restrict__ H, int* __restrict__ partial){
  int i = blockIdx.x*256 + threadIdx.x;
  int v = (i < MTOT) ? H[i] : 0;
  #pragma unroll
  for (int m = 1; m < 64; m <<= 1) v += __shfl_xor(v, m, 64);
  __shared__ int sh[4];
  if ((threadIdx.x & 63) == 0) sh[threadIdx.x >> 6] = v;
  __syncthreads();
  if (threadIdx.x == 0) partial[blockIdx.x] = sh[0] + sh[1] + sh[2] + sh[3];
}

// ---- stage 2: 512-thread scan of MC=391 partials + scalar prep ----
__global__ __launch_bounds__(512) void k_s2p(const int* __restrict__ partial, int* __restrict__ ppref,
                      int* __restrict__ offs, int* __restrict__ bstart,
                      const float* __restrict__ easum,
                      const float* __restrict__ We1, const float* __restrict__ ae1,
                      const float* __restrict__ We2, const float* __restrict__ ae2,
                      float* __restrict__ scal){
  __shared__ int sp[512];
  __shared__ float sh_ea[NBL];
  int t = threadIdx.x;
  if (t < NBL) sh_ea[t] = easum[t];
  if (t >= 448 && t < 448 + HEADS){
    int h = t - 448;
    float s = 0.f;
    for (int c = 0; c < C1; c++) s += We1[h*C1 + c] * ae1[h*C1 + c];
    scal[2 + h] = s;
    scal[7 + h] = We2[h] * ae2[h];
  }
  int v = (t < MC) ? partial[t] : 0;
  sp[t] = v;
  __syncthreads();
  if (t == 511){
    float es = 0.f;
    for (int i = 0; i < NBL; i++) es += sh_ea[i];
    scal[1] = es / (float)N_EDGES;
  }
  for (int off = 1; off < 512; off <<= 1){
    int u = (t >= off) ? sp[t - off] : 0;
    __syncthreads();
    sp[t] += u;
    __syncthreads();
  }
  if (t < MC) ppref[t] = sp[t] - v;
  if (t == 0){ offs[N_NODES] = E2; bstart[NBK] = E2; }
}

// ---- stage 3 ----
__global__ void k_s3(int* __restrict__ H, const int* __restrict__ ppref, int* __restrict__ bstart){
  __shared__ int sp[256];
  int b = blockIdx.x, t = threadIdx.x;
  int i = b*256 + t;
  int v = (i < MTOT) ? H[i] : 0;
  sp[t] = v;
  __syncthreads();
  for (int off = 1; off < 256; off <<= 1){
    int u = (t >= off) ? sp[t - off] : 0;
    __syncthreads();
    sp[t] += u;
    __syncthreads();
  }
  int P = ppref[b] + sp[t] - v;
  if (i < MTOT){
    H[i] = P;
    if (i % NBL == 0) bstart[i / NBL] = P;
  }
}

// ---- scatter into bucket-major packed records (8B/edge) ----
__global__ __launch_bounds__(256) void k_scat(const int* __restrict__ src, const int* __restrict__ dst,
                       const float* __restrict__ ea, const float* __restrict__ scal,
                       const int* __restrict__ H, int2* __restrict__ bpack){
  __shared__ int lofs[NBK];
  int b = blockIdx.x;
  for (int k = threadIdx.x; k < NBK; k += 256) lofs[k] = H[(size_t)k*NBL + b];
  __syncthreads();
  float mean = scal[1];
  int e0 = b*CH, e1 = min(e0 + CH, E2);
  for (int e = e0 + threadIdx.x; e < e1; e += 256){
    int d, s; float a;
    if (e < N_EDGES){ d = dst[e]; s = src[e]; a = ea[e]; }
    else { d = s = e - N_EDGES; a = mean; }
    int pos = atomicAdd(&lofs[d >> 6], 1);
    bpack[pos] = make_int2(s | ((d & 63) << 16), __float_as_int(a));
  }
}

// ---- per-bucket pure counting sort -> offs, edge2 (src|cea16) ----
__global__ __launch_bounds__(256) void k_final2(const int* __restrict__ bstart,
                        const int2* __restrict__ bpack,
                        int* __restrict__ offs, unsigned int* __restrict__ edge2){
  __shared__ int cnt[BSZ], cur[BSZ];
  __shared__ unsigned int s_edge[CAP];
  int k = blockIdx.x, t = threadIdx.x;
  int base = k*BSZ;
  if (t < BSZ) cnt[t] = 0;
  __syncthreads();
  int r0 = bstart[k], r1 = bstart[k + 1];
  int sz = r1 - r0;
  for (int j = r0 + t; j < r1; j += 256) atomicAdd(&cnt[(bpack[j].x >> 16) & 63], 1);
  __syncthreads();
  if (t == 0){
    int run = 0;
    for (int i = 0; i < BSZ; i++){ int c = cnt[i]; cnt[i] = run; cur[i] = run; run += c; }
  }
  __syncthreads();
  if (t < BSZ){
    int n = base + t;
    if (n < N_NODES) offs[n] = r0 + cnt[t];
  }
  if (sz <= CAP){
    for (int j = r0 + t; j < r1; j += 256){
      int2 v = bpack[j];
      int lp = atomicAdd(&cur[(v.x >> 16) & 63], 1);
      s_edge[lp] = (unsigned int)(v.x & 0xFFFF) |
                   ((unsigned int)__half_as_ushort(__float2half(__int_as_float(v.y))) << 16);
    }
    __syncthreads();
    for (int i = t; i < sz; i += 256) edge2[r0 + i] = s_edge[i];
  } else {
    for (int j = r0 + t; j < r1; j += 256){
      int2 v = bpack[j];
      int pos = r0 + atomicAdd(&cur[(v.x >> 16) & 63], 1);
      edge2[pos] = (unsigned int)(v.x & 0xFFFF) |
                   ((unsigned int)__half_as_ushort(__float2half(__int_as_float(v.y))) << 16);
    }
  }
}

// ---- layer 1 aggregate: inline softmax, as1 in-row, 40 threads/node, fp8 quad gathers ----
__global__ __launch_bounds__(320) void k_agg1(const int* __restrict__ offs,
                      const unsigned int* __restrict__ edge2,
                      const float* __restrict__ ad1p, const float* __restrict__ scal,
                      const unsigned short* __restrict__ h1q,
                      const float* __restrict__ b1, __half* __restrict__ x2h){
  int nl = threadIdx.x / 40;           // 8 nodes per block
  int c4 = threadIdx.x - nl*40;        // channel quad
  int n  = blockIdx.x*8 + nl;
  int h  = c4 >> 3;
  float wd  = scal[2 + h];
  float adn = ad1p[n*8 + h];
  const unsigned int* h1row = (const unsigned int*)h1q;
  const __half* as1row = (const __half*)h1q;
  int j0 = offs[n], j1 = offs[n + 1];
  float a0 = 0.f, a1 = 0.f, a2 = 0.f, a3 = 0.f, den = 0.f;
  int j = j0;
  for (; j + 7 < j1; j += 8){
    uint4 sa = *(const uint4*)(edge2 + j);
    uint4 sb = *(const uint4*)(edge2 + j + 4);
    unsigned int e0 = sa.x, e1 = sa.y, e2v = sa.z, e3 = sa.w;
    unsigned int e4 = sb.x, e5 = sb.y, e6 = sb.z, e7 = sb.w;
    int s0 = e0 & 0xFFFF, s1 = e1 & 0xFFFF, s2 = e2v & 0xFFFF, s3 = e3 & 0xFFFF;
    int s4 = e4 & 0xFFFF, s5 = e5 & 0xFFFF, s6 = e6 & 0xFFFF, s7 = e7 & 0xFFFF;
    unsigned int r0 = h1row[(size_t)s0*RSW + c4];
    unsigned int r1 = h1row[(size_t)s1*RSW + c4];
    unsigned int r2 = h1row[(size_t)s2*RSW + c4];
    unsigned int r3 = h1row[(size_t)s3*RSW + c4];
    unsigned int r4 = h1row[(size_t)s4*RSW + c4];
    unsigned int r5 = h1row[(size_t)s5*RSW + c4];
    unsigned int r6 = h1row[(size_t)s6*RSW + c4];
    unsigned int r7 = h1row[(size_t)s7*RSW + c4];
    float g0 = __half2float(as1row[(size_t)s0*RSU + 80 + h]);
    float g1 = __half2float(as1row[(size_t)s1*RSU + 80 + h]);
    float g2 = __half2float(as1row[(size_t)s2*RSU + 80 + h]);
    float g3 = __half2float(as1row[(size_t)s3*RSU + 80 + h]);
    float g4 = __half2float(as1row[(size_t)s4*RSU + 80 + h]);
    float g5 = __half2float(as1row[(size_t)s5*RSU + 80 + h]);
    float g6 = __half2float(as1row[(size_t)s6*RSU + 80 + h]);
    float g7 = __half2float(as1row[(size_t)s7*RSU + 80 + h]);
    float c0 = __half2float(__ushort_as_half((unsigned short)(e0 >> 16)));
    float c1 = __half2float(__ushort_as_half((unsigned short)(e1 >> 16)));
    float c2 = __half2float(__ushort_as_half((unsigned short)(e2v >> 16)));
    float c3 = __half2float(__ushort_as_half((unsigned short)(e3 >> 16)));
    float c4v = __half2float(__ushort_as_half((unsigned short)(e4 >> 16)));
    float c5v = __half2float(__ushort_as_half((unsigned short)(e5 >> 16)));
    float c6 = __half2float(__ushort_as_half((unsigned short)(e6 >> 16)));
    float c7 = __half2float(__ushort_as_half((unsigned short)(e7 >> 16)));
    float l0 = g0 + adn + c0*wd;  l0 = fminf(fmaxf(l0, 0.2f*l0), 10.f);
    float l1 = g1 + adn + c1*wd;  l1 = fminf(fmaxf(l1, 0.2f*l1), 10.f);
    float l2 = g2 + adn + c2*wd;  l2 = fminf(fmaxf(l2, 0.2f*l2), 10.f);
    float l3 = g3 + adn + c3*wd;  l3 = fminf(fmaxf(l3, 0.2f*l3), 10.f);
    float l4 = g4 + adn + c4v*wd; l4 = fminf(fmaxf(l4, 0.2f*l4), 10.f);
    float l5 = g5 + adn + c5v*wd; l5 = fminf(fmaxf(l5, 0.2f*l5), 10.f);
    float l6 = g6 + adn + c6*wd;  l6 = fminf(fmaxf(l6, 0.2f*l6), 10.f);
    float l7 = g7 + adn + c7*wd;  l7 = fminf(fmaxf(l7, 0.2f*l7), 10.f);
    float p0 = __expf(l0), p1 = __expf(l1), p2 = __expf(l2), p3 = __expf(l3);
    float p4 = __expf(l4), p5 = __expf(l5), p6 = __expf(l6), p7 = __expf(l7);
    den += p0 + p1 + p2 + p3 + p4 + p5 + p6 + p7;
    float4 f0 = fp8x4_to_f32(r0), f1 = fp8x4_to_f32(r1);
    float4 f2 = fp8x4_to_f32(r2), f3 = fp8x4_to_f32(r3);
    float4 f4 = fp8x4_to_f32(r4), f5 = fp8x4_to_f32(r5);
    float4 f6 = fp8x4_to_f32(r6), f7 = fp8x4_to_f32(r7);
    a0 += p0*f0.x; a1 += p0*f0.y; a2 += p0*f0.z; a3 += p0*f0.w;
    a0 += p1*f1.x; a1 += p1*f1.y; a2 += p1*f1.z; a3 += p1*f1.w;
    a0 += p2*f2.x; a1 += p2*f2.y; a2 += p2*f2.z; a3 += p2*f2.w;
    a0 += p3*f3.x; a1 += p3*f3.y; a2 += p3*f3.z; a3 += p3*f3.w;
    a0 += p4*f4.x; a1 += p4*f4.y; a2 += p4*f4.z; a3 += p4*f4.w;
    a0 += p5*f5.x; a1 += p5*f5.y; a2 += p5*f5.z; a3 += p5*f5.w;
    a0 += p6*f6.x; a1 += p6*f6.y; a2 += p6*f6.z; a3 += p6*f6.w;
    a0 += p7*f7.x; a1 += p7*f7.y; a2 += p7*f7.z; a3 += p7*f7.w;
  }
  for (; j < j1; ++j){
    unsigned int e = edge2[j];
    int s = e & 0xFFFF;
    float c = __half2float(__ushort_as_half((unsigned short)(e >> 16)));
    float g = __half2float(as1row[(size_t)s*RSU + 80 + h]);
    float lg = g + adn + c*wd;
    lg = fminf(fmaxf(lg, 0.2f*lg), 10.f);
    float p = __expf(lg);
    den += p;
    float4 f = fp8x4_to_f32(h1row[(size_t)s*RSW + c4]);
    a0 += p*f.x; a1 += p*f.y; a2 += p*f.z; a3 += p*f.w;
  }
  float inv = 1.f / (den + 1e-16f);
  float4 bb = *(const float4*)(b1 + 4*c4);
  float v0 = fmaxf(a0*inv + bb.x, 0.f);
  float v1 = fmaxf(a1*inv + bb.y, 0.f);
  float v2 = fmaxf(a2*inv + bb.z, 0.f);
  float v3 = fmaxf(a3*inv + bb.w, 0.f);
  __half2 o0 = __floats2half2_rn(v0, v1);
  __half2 o1 = __floats2half2_rn(v2, v3);
  *(uint2*)(x2h + (size_t)n*F1 + 4*c4) =
      make_uint2(*(unsigned int*)&o0, *(unsigned int*)&o1);
}

// ---- layer 2: h2 = x2h@W2 -> packed fp16 G16 ([0..4]=h2, [5..9]=as2) + ad2p ----
__global__ __launch_bounds__(256) void k_h2(const __half* __restrict__ x2h, const float* __restrict__ W2,
                    const float* __restrict__ asw2, const float* __restrict__ adw2,
                    __half* __restrict__ G16, float* __restrict__ ad2p){
  __shared__ float sW[F1*HEADS];
  for (int k = threadIdx.x; k < F1*HEADS; k += 256) sW[k] = W2[k];
  __syncthreads();
  int w = threadIdx.x >> 6, l = threadIdx.x & 63;
  int n = blockIdx.x*4 + w;
  const __half2* x22 = (const __half2*)x2h;
  float acc[HEADS] = {0.f, 0.f, 0.f, 0.f, 0.f};
  for (int k2 = l; k2 < 80; k2 += 64){
    float2 f = __half22float2(x22[(size_t)n*80 + k2]);
    #pragma unroll
    for (int h = 0; h < HEADS; h++)
      acc[h] += f.x * sW[(2*k2)*HEADS + h] + f.y * sW[(2*k2+1)*HEADS + h];
  }
  #pragma unroll
  for (int m = 1; m < 64; m <<= 1){
    #pragma unroll
    for (int h = 0; h < HEADS; h++) acc[h] += __shfl_xor(acc[h], m, 64);
  }
  if (l == 0){
    #pragma unroll
    for (int h = 0; h < HEADS; h++){
      G16[(size_t)n*16 + h]     = __float2half(acc[h]);
      G16[(size_t)n*16 + 5 + h] = __float2half(acc[h] * asw2[h]);
      ad2p[n*8 + h]             = acc[h] * adw2[h];
    }
    #pragma unroll
    for (int z = 10; z < 16; z++) G16[(size_t)n*16 + z] = __float2half(0.f);
  }
}

// ---- layer 2: 16-lane-group-per-node softmax aggregate + mean + linear + sigmoid ----
__global__ __launch_bounds__(256) void k_agg2(const int* __restrict__ offs,
                      const unsigned int* __restrict__ edge2,
                      const __half* __restrict__ G16, const float* __restrict__ ad2p,
                      const float* __restrict__ scal,
                      const float* __restrict__ b2, const float* __restrict__ Wlin,
                      float* __restrict__ out){
  int grp = threadIdx.x >> 4;
  int l16 = threadIdx.x & 15;
  int n = blockIdx.x*16 + grp;
  float adn[HEADS], wd[HEADS];
  #pragma unroll
  for (int h = 0; h < HEADS; h++){ adn[h] = ad2p[n*8 + h]; wd[h] = scal[7 + h]; }
  int j0 = offs[n], j1 = offs[n + 1];

  float den[HEADS] = {0,0,0,0,0};
  float ac[HEADS]  = {0,0,0,0,0};
  for (int j = j0 + l16; j < j1; j += 16){
    unsigned int e = edge2[j];
    int s = e & 0xFFFF;
    float c = __half2float(__ushort_as_half((unsigned short)(e >> 16)));
    const __half* gs = G16 + (size_t)s*16;
    union { uint4 u; __half2 h[4]; } U; U.u = *(const uint4*)gs;
    union { uint2 u; __half2 h[2]; } V; V.u = *(const uint2*)(gs + 8);
    float2 p01 = __half22float2(U.h[0]);
    float2 p23 = __half22float2(U.h[1]);
    float2 p45 = __half22float2(U.h[2]);
    float2 p67 = __half22float2(U.h[3]);
    float2 p89 = __half22float2(V.h[0]);
    float hv[HEADS] = {p01.x, p01.y, p23.x, p23.y, p45.x};
    float av[HEADS] = {p45.y, p67.x, p67.y, p89.x, p89.y};
    #pragma unroll
    for (int h = 0; h < HEADS; h++){
      float lg = av[h] + adn[h] + c*wd[h];
      lg = fmaxf(lg, 0.2f*lg);
      lg = fminf(lg, 50.f);
      float p = __expf(lg);
      den[h] += p;
      ac[h]  += p * hv[h];
    }
  }
  #pragma unroll
  for (int m = 1; m < 16; m <<= 1){
    #pragma unroll
    for (int h = 0; h < HEADS; h++){
      den[h] += __shfl_xor(den[h], m, 16);
      ac[h]  += __shfl_xor(ac[h], m, 16);
    }
  }
  if (l16 == 0){
    float v = 0.f;
    #pragma unroll
    for (int h = 0; h < HEADS; h++) v += ac[h] / (den[h] + 1e-16f);
    v = v * (1.f/HEADS) + b2[0];
    v *= Wlin[0];
    out[n] = 1.f / (1.f + __expf(-v));
  }
}

extern "C" void kernel_launch(void* const* d_in, const int* in_sizes, int n_in,
                              void* d_out, int out_size, void* d_ws, size_t ws_size,
                              hipStream_t stream) {
  const float* x    = (const float*)d_in[0];
  const float* ea   = (const float*)d_in[1];
  const int*   src  = (const int*)d_in[2];
  const int*   dst  = (const int*)d_in[3];
  const float* W1   = (const float*)d_in[4];
  const float* as1w = (const float*)d_in[5];
  const float* ad1w = (const float*)d_in[6];
  const float* We1  = (const float*)d_in[7];
  const float* ae1  = (const float*)d_in[8];
  const float* b1   = (const float*)d_in[9];
  const float* W2   = (const float*)d_in[10];
  const float* as2w = (const float*)d_in[11];
  const float* ad2w = (const float*)d_in[12];
  const float* We2  = (const float*)d_in[13];
  const float* ae2  = (const float*)d_in[14];
  const float* b2   = (const float*)d_in[15];
  const float* Wlin = (const float*)d_in[16];

  char* ws = (char*)d_ws;
  float* scal   = (float*)(ws + OFF_SCAL);
  int*   H      = (int*)  (ws + OFF_H);
  float* easum  = (float*)(ws + OFF_EAS);
  int*   part   = (int*)  (ws + OFF_PART);
  int*   ppref  = (int*)  (ws + OFF_PPREF);
  int*   bstart = (int*)  (ws + OFF_BST);
  int*   offs   = (int*)  (ws + OFF_OFFS);
  int2*  bpack  = (int2*) (ws + OFF_BPACK);
  unsigned int* edge2 = (unsigned int*)(ws + OFF_EDG);
  float* ad1p   = (float*)(ws + OFF_AD1P);
  __half* G16   = (__half*)(ws + OFF_G16);
  float* ad2p   = (float*)(ws + OFF_AD2P);
  unsigned short* h1q = (unsigned short*)(ws + OFF_H1Q);
  __half* x2h   = (__half*)(ws + OFF_X2H);
  float* outp   = (float*)d_out;

  k_init   <<<GRID_H1 + NBL, 320, 0, stream>>>(x, W1, as1w, ad1w, h1q, ad1p,
                                               dst, ea, H, easum);
  k_s1     <<<MC, 256, 0, stream>>>(H, part);
  k_s2p    <<<1, 512, 0, stream>>>(part, ppref, offs, bstart, easum, We1, ae1, We2, ae2, scal);
  k_s3     <<<MC, 256, 0, stream>>>(H, ppref, bstart);
  k_scat   <<<NBL, 256, 0, stream>>>(src, dst, ea, scal, H, bpack);
  k_final2 <<<NBK, 256, 0, stream>>>(bstart, bpack, offs, edge2);

  k_agg1   <<<N_NODES/8, 320, 0, stream>>>(offs, edge2, ad1p, scal, h1q, b1, x2h);
  k_h2     <<<N_NODES/4, 256, 0, stream>>>(x2h, W2, as2w, ad2w, G16, ad2p);
  k_agg2   <<<N_NODES/16, 256, 0, stream>>>(offs, edge2, G16, ad2p, scal, b2, Wlin, outp);
}

// Round 20
// 227.929 us; speedup vs baseline: 1.0025x; 1.0025x over previous
//
#include <hip/hip_runtime.h>
#include <hip/hip_fp16.h>
#include <math.h>

#define N_NODES 50000
#define N_EDGES 800000
#define E2 (N_EDGES + N_NODES)   // 850000
#define HEADS 5
#define C1 32
#define F1 160

// counting-sort CSR build (64-node buckets)
#define BSZ 64
#define NBK 782                  // 782*64 = 50048 >= N
#define NBL 128
#define CH  6641                 // 128*6641 >= E2
#define MTOT (NBK*NBL)           // 100096
#define MC  391                  // ceil(MTOT/256)
#define GRID_H1 (N_NODES/4)      // 12500 h1 blocks in k_init
#define CAP 1408                 // LDS staging cap per 64-node bucket

static constexpr size_t alignup(size_t x){ return (x + 255) & ~size_t(255); }
static constexpr size_t OFF_SCAL  = 0;                                           // 64 f
static constexpr size_t OFF_H     = alignup(OFF_SCAL + 64*4);                    // MTOT i
static constexpr size_t OFF_EAS   = alignup(OFF_H    + (size_t)MTOT*4);          // NBL f
static constexpr size_t OFF_PART  = alignup(OFF_EAS  + (size_t)NBL*4);           // MC i
static constexpr size_t OFF_PPREF = alignup(OFF_PART + (size_t)MC*4);            // MC i
static constexpr size_t OFF_BST   = alignup(OFF_PPREF+ (size_t)MC*4);            // NBK+1
static constexpr size_t OFF_OFFS  = alignup(OFF_BST  + (size_t)(NBK+1)*4);       // N+1
static constexpr size_t OFF_BPACK = alignup(OFF_OFFS + (size_t)(N_NODES+1)*4);   // E2 int2
static constexpr size_t OFF_EDG   = alignup(OFF_BPACK+ (size_t)E2*8);            // E2 u32
static constexpr size_t OFF_AS1P  = alignup(OFF_EDG  + (size_t)E2*4);            // N*8 f
static constexpr size_t OFF_AD1P  = alignup(OFF_AS1P + (size_t)N_NODES*8*4);
static constexpr size_t OFF_G16   = alignup(OFF_AD1P + (size_t)N_NODES*8*4);     // N*16 half
static constexpr size_t OFF_AD2P  = alignup(OFF_G16  + (size_t)N_NODES*16*2);    // N*8 f
static constexpr size_t OFF_H1Q   = alignup(OFF_AD2P + (size_t)N_NODES*8*4);     // N*160 fp8
static constexpr size_t OFF_X2H   = alignup(OFF_H1Q  + (size_t)N_NODES*F1);      // N*160 half

typedef float vf2 __attribute__((ext_vector_type(2)));
__device__ __forceinline__ float4 fp8x4_to_f32(unsigned int r){
  vf2 lo = __builtin_amdgcn_cvt_pk_f32_fp8((int)r, false);
  vf2 hi = __builtin_amdgcn_cvt_pk_f32_fp8((int)r, true);
  return make_float4(lo.x, lo.y, hi.x, hi.y);
}

// ---- fused: layer-1 projection (fp8 h1 out) + coarse histogram (last NBL blocks) ----
__global__ __launch_bounds__(320) void k_init(const float* __restrict__ x, const float* __restrict__ W1,
                       const float* __restrict__ as1w, const float* __restrict__ ad1w,
                       unsigned short* __restrict__ h1q, float* __restrict__ as1p, float* __restrict__ ad1p,
                       const int* __restrict__ dst, const float* __restrict__ ea,
                       int* __restrict__ H, float* __restrict__ easum){
  __shared__ float sW[5*F1];
  int t = threadIdx.x;
  if (blockIdx.x < GRID_H1){
    for (int k = t; k < 5*F1; k += 320) sW[k] = W1[k];
    __syncthreads();
    int nl = t / 80;
    int c  = t - nl*80;
    int n  = blockIdx.x*4 + nl;
    int c0 = 2*c;
    float hv0 = 0.f, hv1 = 0.f;
    #pragma unroll
    for (int f = 0; f < 5; f++){
      float xv = x[n*5 + f];
      hv0 += xv * sW[f*F1 + c0];
      hv1 += xv * sW[f*F1 + c0 + 1];
    }
    int pk = __builtin_amdgcn_cvt_pk_fp8_f32(hv0, hv1, 0, false);
    h1q[n*80 + c] = (unsigned short)(pk & 0xFFFF);
    float vs = hv0*as1w[c0] + hv1*as1w[c0+1];
    float vd = hv0*ad1w[c0] + hv1*ad1w[c0+1];
    #pragma unroll
    for (int m = 8; m >= 1; m >>= 1){
      vs += __shfl_xor(vs, m, 64);
      vd += __shfl_xor(vd, m, 64);
    }
    if ((c & 15) == 0){
      int h = c >> 4;
      as1p[n*8 + h] = vs;
      ad1p[n*8 + h] = vd;
    }
  } else {
    int* hist = (int*)sW;
    float* wsum = (float*)&hist[NBK + 1];
    for (int k = t; k < NBK; k += 320) hist[k] = 0;
    __syncthreads();
    int b = blockIdx.x - GRID_H1;
    int e0 = b*CH, e1 = min(e0 + CH, E2);
    float s = 0.f;
    for (int e = e0 + t; e < e1; e += 320){
      int d;
      if (e < N_EDGES){ d = dst[e]; s += ea[e]; }
      else d = e - N_EDGES;
      atomicAdd(&hist[d >> 6], 1);
    }
    #pragma unroll
    for (int m = 1; m < 64; m <<= 1) s += __shfl_xor(s, m, 64);
    if ((t & 63) == 0) wsum[t >> 6] = s;
    __syncthreads();
    for (int k = t; k < NBK; k += 320) H[(size_t)k*NBL + b] = hist[k];
    if (t == 0) easum[b] = wsum[0] + wsum[1] + wsum[2] + wsum[3] + wsum[4];
  }
}

// ---- parallel scan, stage 1 ----
__global__ void k_s1(const int* __restrict__ H, int* __restrict__ partial){
  int i = blockIdx.x*256 + threadIdx.x;
  int v = (i < MTOT) ? H[i] : 0;
  #pragma unroll
  for (int m = 1; m < 64; m <<= 1) v += __shfl_xor(v, m, 64);
  __shared__ int sh[4];
  if ((threadIdx.x & 63) == 0) sh[threadIdx.x >> 6] = v;
  __syncthreads();
  if (threadIdx.x == 0) partial[blockIdx.x] = sh[0] + sh[1] + sh[2] + sh[3];
}

// ---- stage 2: 512-thread scan of MC=391 partials + scalar prep ----
__global__ __launch_bounds__(512) void k_s2p(const int* __restrict__ partial, int* __restrict__ ppref,
                      int* __restrict__ offs, int* __restrict__ bstart,
                      const float* __restrict__ easum,
                      const float* __restrict__ We1, const float* __restrict__ ae1,
                      const float* __restrict__ We2, const float* __restrict__ ae2,
                      float* __restrict__ scal){
  __shared__ int sp[512];
  __shared__ float sh_ea[NBL];
  int t = threadIdx.x;
  if (t < NBL) sh_ea[t] = easum[t];
  if (t >= 448 && t < 448 + HEADS){
    int h = t - 448;
    float s = 0.f;
    for (int c = 0; c < C1; c++) s += We1[h*C1 + c] * ae1[h*C1 + c];
    scal[2 + h] = s;
    scal[7 + h] = We2[h] * ae2[h];
  }
  int v = (t < MC) ? partial[t] : 0;
  sp[t] = v;
  __syncthreads();
  if (t == 511){
    float es = 0.f;
    for (int i = 0; i < NBL; i++) es += sh_ea[i];
    scal[1] = es / (float)N_EDGES;
  }
  for (int off = 1; off < 512; off <<= 1){
    int u = (t >= off) ? sp[t - off] : 0;
    __syncthreads();
    sp[t] += u;
    __syncthreads();
  }
  if (t < MC) ppref[t] = sp[t] - v;
  if (t == 0){ offs[N_NODES] = E2; bstart[NBK] = E2; }
}

// ---- stage 3 ----
__global__ void k_s3(int* __restrict__ H, const int* __restrict__ ppref, int* __restrict__ bstart){
  __shared__ int sp[256];
  int b = blockIdx.x, t = threadIdx.x;
  int i = b*256 + t;
  int v = (i < MTOT) ? H[i] : 0;
  sp[t] = v;
  __syncthreads();
  for (int off = 1; off < 256; off <<= 1){
    int u = (t >= off) ? sp[t - off] : 0;
    __syncthreads();
    sp[t] += u;
    __syncthreads();
  }
  int P = ppref[b] + sp[t] - v;
  if (i < MTOT){
    H[i] = P;
    if (i % NBL == 0) bstart[i / NBL] = P;
  }
}

// ---- scatter into bucket-major packed records (8B/edge) ----
__global__ __launch_bounds__(256) void k_scat(const int* __restrict__ src, const int* __restrict__ dst,
                       const float* __restrict__ ea, const float* __restrict__ scal,
                       const int* __restrict__ H, int2* __restrict__ bpack){
  __shared__ int lofs[NBK];
  int b = blockIdx.x;
  for (int k = threadIdx.x; k < NBK; k += 256) lofs[k] = H[(size_t)k*NBL + b];
  __syncthreads();
  float mean = scal[1];
  int e0 = b*CH, e1 = min(e0 + CH, E2);
  for (int e = e0 + threadIdx.x; e < e1; e += 256){
    int d, s; float a;
    if (e < N_EDGES){ d = dst[e]; s = src[e]; a = ea[e]; }
    else { d = s = e - N_EDGES; a = mean; }
    int pos = atomicAdd(&lofs[d >> 6], 1);
    bpack[pos] = make_int2(s | ((d & 63) << 16), __float_as_int(a));
  }
}

// ---- per-bucket pure counting sort -> offs, edge2 (src|cea16) ----
__global__ __launch_bounds__(256) void k_final2(const int* __restrict__ bstart,
                        const int2* __restrict__ bpack,
                        int* __restrict__ offs, unsigned int* __restrict__ edge2){
  __shared__ int cnt[BSZ], cur[BSZ];
  __shared__ unsigned int s_edge[CAP];
  int k = blockIdx.x, t = threadIdx.x;
  int base = k*BSZ;
  if (t < BSZ) cnt[t] = 0;
  __syncthreads();
  int r0 = bstart[k], r1 = bstart[k + 1];
  int sz = r1 - r0;
  for (int j = r0 + t; j < r1; j += 256) atomicAdd(&cnt[(bpack[j].x >> 16) & 63], 1);
  __syncthreads();
  if (t == 0){
    int run = 0;
    for (int i = 0; i < BSZ; i++){ int c = cnt[i]; cnt[i] = run; cur[i] = run; run += c; }
  }
  __syncthreads();
  if (t < BSZ){
    int n = base + t;
    if (n < N_NODES) offs[n] = r0 + cnt[t];
  }
  if (sz <= CAP){
    for (int j = r0 + t; j < r1; j += 256){
      int2 v = bpack[j];
      int lp = atomicAdd(&cur[(v.x >> 16) & 63], 1);
      s_edge[lp] = (unsigned int)(v.x & 0xFFFF) |
                   ((unsigned int)__half_as_ushort(__float2half(__int_as_float(v.y))) << 16);
    }
    __syncthreads();
    for (int i = t; i < sz; i += 256) edge2[r0 + i] = s_edge[i];
  } else {
    for (int j = r0 + t; j < r1; j += 256){
      int2 v = bpack[j];
      int pos = r0 + atomicAdd(&cur[(v.x >> 16) & 63], 1);
      edge2[pos] = (unsigned int)(v.x & 0xFFFF) |
                   ((unsigned int)__half_as_ushort(__float2half(__int_as_float(v.y))) << 16);
    }
  }
}

// ---- layer 1 aggregate: lane-cooperative softmax (1 exp/edge per head group), fp8 quads ----
__global__ __launch_bounds__(320) void k_agg1(const int* __restrict__ offs,
                      const unsigned int* __restrict__ edge2,
                      const float* __restrict__ as1p, const float* __restrict__ ad1p,
                      const float* __restrict__ scal,
                      const unsigned short* __restrict__ h1q,
                      const float* __restrict__ b1, __half* __restrict__ x2h){
  int nl = threadIdx.x / 40;           // 8 nodes per block
  int c4 = threadIdx.x - nl*40;        // channel quad
  int n  = blockIdx.x*8 + nl;
  int h  = c4 >> 3;
  int lk = c4 & 7;                     // lane index within 8-lane head group (8-aligned in wave)
  float wd  = scal[2 + h];
  float adn = ad1p[n*8 + h];
  const unsigned int* h1row = (const unsigned int*)h1q;
  int j0 = offs[n], j1 = offs[n + 1];
  float a0 = 0.f, a1 = 0.f, a2 = 0.f, a3 = 0.f, den = 0.f;
  int j = j0;
  for (; j + 7 < j1; j += 8){
    uint4 sa = *(const uint4*)(edge2 + j);
    uint4 sb = *(const uint4*)(edge2 + j + 4);
    int s0 = sa.x & 0xFFFF, s1 = sa.y & 0xFFFF, s2 = sa.z & 0xFFFF, s3 = sa.w & 0xFFFF;
    int s4 = sb.x & 0xFFFF, s5 = sb.y & 0xFFFF, s6 = sb.z & 0xFFFF, s7 = sb.w & 0xFFFF;
    unsigned int r0 = h1row[(size_t)s0*40 + c4];
    unsigned int r1 = h1row[(size_t)s1*40 + c4];
    unsigned int r2 = h1row[(size_t)s2*40 + c4];
    unsigned int r3 = h1row[(size_t)s3*40 + c4];
    unsigned int r4 = h1row[(size_t)s4*40 + c4];
    unsigned int r5 = h1row[(size_t)s5*40 + c4];
    unsigned int r6 = h1row[(size_t)s6*40 + c4];
    unsigned int r7 = h1row[(size_t)s7*40 + c4];
    // lane-cooperative: lane lk handles edge j+lk's logit+exp
    unsigned int ek = edge2[j + lk];
    int sk = ek & 0xFFFF;
    float ck = __half2float(__ushort_as_half((unsigned short)(ek >> 16)));
    float gk = as1p[sk*8 + h];
    float lgk = gk + adn + ck*wd;
    lgk = fminf(fmaxf(lgk, 0.2f*lgk), 10.f);
    float pk = __expf(lgk);
    float p0 = __shfl(pk, 0, 8), p1 = __shfl(pk, 1, 8);
    float p2 = __shfl(pk, 2, 8), p3 = __shfl(pk, 3, 8);
    float p4 = __shfl(pk, 4, 8), p5 = __shfl(pk, 5, 8);
    float p6 = __shfl(pk, 6, 8), p7 = __shfl(pk, 7, 8);
    den += p0 + p1 + p2 + p3 + p4 + p5 + p6 + p7;
    float4 f0 = fp8x4_to_f32(r0), f1 = fp8x4_to_f32(r1);
    float4 f2 = fp8x4_to_f32(r2), f3 = fp8x4_to_f32(r3);
    float4 f4 = fp8x4_to_f32(r4), f5 = fp8x4_to_f32(r5);
    float4 f6 = fp8x4_to_f32(r6), f7 = fp8x4_to_f32(r7);
    a0 += p0*f0.x; a1 += p0*f0.y; a2 += p0*f0.z; a3 += p0*f0.w;
    a0 += p1*f1.x; a1 += p1*f1.y; a2 += p1*f1.z; a3 += p1*f1.w;
    a0 += p2*f2.x; a1 += p2*f2.y; a2 += p2*f2.z; a3 += p2*f2.w;
    a0 += p3*f3.x; a1 += p3*f3.y; a2 += p3*f3.z; a3 += p3*f3.w;
    a0 += p4*f4.x; a1 += p4*f4.y; a2 += p4*f4.z; a3 += p4*f4.w;
    a0 += p5*f5.x; a1 += p5*f5.y; a2 += p5*f5.z; a3 += p5*f5.w;
    a0 += p6*f6.x; a1 += p6*f6.y; a2 += p6*f6.z; a3 += p6*f6.w;
    a0 += p7*f7.x; a1 += p7*f7.y; a2 += p7*f7.z; a3 += p7*f7.w;
  }
  for (; j < j1; ++j){
    unsigned int e = edge2[j];
    int s = e & 0xFFFF;
    float c = __half2float(__ushort_as_half((unsigned short)(e >> 16)));
    float g = as1p[s*8 + h];
    float lg = g + adn + c*wd;
    lg = fminf(fmaxf(lg, 0.2f*lg), 10.f);
    float p = __expf(lg);
    den += p;
    float4 f = fp8x4_to_f32(h1row[(size_t)s*40 + c4]);
    a0 += p*f.x; a1 += p*f.y; a2 += p*f.z; a3 += p*f.w;
  }
  float inv = 1.f / (den + 1e-16f);
  float4 bb = *(const float4*)(b1 + 4*c4);
  float v0 = fmaxf(a0*inv + bb.x, 0.f);
  float v1 = fmaxf(a1*inv + bb.y, 0.f);
  float v2 = fmaxf(a2*inv + bb.z, 0.f);
  float v3 = fmaxf(a3*inv + bb.w, 0.f);
  __half2 o0 = __floats2half2_rn(v0, v1);
  __half2 o1 = __floats2half2_rn(v2, v3);
  *(uint2*)(x2h + (size_t)n*F1 + 4*c4) =
      make_uint2(*(unsigned int*)&o0, *(unsigned int*)&o1);
}

// ---- layer 2: h2 = x2h@W2 -> packed fp16 G16 ([0..4]=h2, [5..9]=as2) + ad2p ----
__global__ __launch_bounds__(256) void k_h2(const __half* __restrict__ x2h, const float* __restrict__ W2,
                    const float* __restrict__ asw2, const float* __restrict__ adw2,
                    __half* __restrict__ G16, float* __restrict__ ad2p){
  __shared__ float sW[F1*HEADS];
  for (int k = threadIdx.x; k < F1*HEADS; k += 256) sW[k] = W2[k];
  __syncthreads();
  int w = threadIdx.x >> 6, l = threadIdx.x & 63;
  int n = blockIdx.x*4 + w;
  const __half2* x22 = (const __half2*)x2h;
  float acc[HEADS] = {0.f, 0.f, 0.f, 0.f, 0.f};
  for (int k2 = l; k2 < 80; k2 += 64){
    float2 f = __half22float2(x22[(size_t)n*80 + k2]);
    #pragma unroll
    for (int h = 0; h < HEADS; h++)
      acc[h] += f.x * sW[(2*k2)*HEADS + h] + f.y * sW[(2*k2+1)*HEADS + h];
  }
  #pragma unroll
  for (int m = 1; m < 64; m <<= 1){
    #pragma unroll
    for (int h = 0; h < HEADS; h++) acc[h] += __shfl_xor(acc[h], m, 64);
  }
  if (l == 0){
    #pragma unroll
    for (int h = 0; h < HEADS; h++){
      G16[(size_t)n*16 + h]     = __float2half(acc[h]);
      G16[(size_t)n*16 + 5 + h] = __float2half(acc[h] * asw2[h]);
      ad2p[n*8 + h]             = acc[h] * adw2[h];
    }
    #pragma unroll
    for (int z = 10; z < 16; z++) G16[(size_t)n*16 + z] = __float2half(0.f);
  }
}

// ---- layer 2: 16-lane-group-per-node softmax aggregate + mean + linear + sigmoid ----
__global__ __launch_bounds__(256) void k_agg2(const int* __restrict__ offs,
                      const unsigned int* __restrict__ edge2,
                      const __half* __restrict__ G16, const float* __restrict__ ad2p,
                      const float* __restrict__ scal,
                      const float* __restrict__ b2, const float* __restrict__ Wlin,
                      float* __restrict__ out){
  int grp = threadIdx.x >> 4;
  int l16 = threadIdx.x & 15;
  int n = blockIdx.x*16 + grp;
  float adn[HEADS], wd[HEADS];
  #pragma unroll
  for (int h = 0; h < HEADS; h++){ adn[h] = ad2p[n*8 + h]; wd[h] = scal[7 + h]; }
  int j0 = offs[n], j1 = offs[n + 1];

  float den[HEADS] = {0,0,0,0,0};
  float ac[HEADS]  = {0,0,0,0,0};
  for (int j = j0 + l16; j < j1; j += 16){
    unsigned int e = edge2[j];
    int s = e & 0xFFFF;
    float c = __half2float(__ushort_as_half((unsigned short)(e >> 16)));
    const __half* gs = G16 + (size_t)s*16;
    union { uint4 u; __half2 h[4]; } U; U.u = *(const uint4*)gs;
    union { uint2 u; __half2 h[2]; } V; V.u = *(const uint2*)(gs + 8);
    float2 p01 = __half22float2(U.h[0]);
    float2 p23 = __half22float2(U.h[1]);
    float2 p45 = __half22float2(U.h[2]);
    float2 p67 = __half22float2(U.h[3]);
    float2 p89 = __half22float2(V.h[0]);
    float hv[HEADS] = {p01.x, p01.y, p23.x, p23.y, p45.x};
    float av[HEADS] = {p45.y, p67.x, p67.y, p89.x, p89.y};
    #pragma unroll
    for (int h = 0; h < HEADS; h++){
      float lg = av[h] + adn[h] + c*wd[h];
      lg = fmaxf(lg, 0.2f*lg);
      lg = fminf(lg, 50.f);
      float p = __expf(lg);
      den[h] += p;
      ac[h]  += p * hv[h];
    }
  }
  #pragma unroll
  for (int m = 1; m < 16; m <<= 1){
    #pragma unroll
    for (int h = 0; h < HEADS; h++){
      den[h] += __shfl_xor(den[h], m, 16);
      ac[h]  += __shfl_xor(ac[h], m, 16);
    }
  }
  if (l16 == 0){
    float v = 0.f;
    #pragma unroll
    for (int h = 0; h < HEADS; h++) v += ac[h] / (den[h] + 1e-16f);
    v = v * (1.f/HEADS) + b2[0];
    v *= Wlin[0];
    out[n] = 1.f / (1.f + __expf(-v));
  }
}

extern "C" void kernel_launch(void* const* d_in, const int* in_sizes, int n_in,
                              void* d_out, int out_size, void* d_ws, size_t ws_size,
                              hipStream_t stream) {
  const float* x    = (const float*)d_in[0];
  const float* ea   = (const float*)d_in[1];
  const int*   src  = (const int*)d_in[2];
  const int*   dst  = (const int*)d_in[3];
  const float* W1   = (const float*)d_in[4];
  const float* as1w = (const float*)d_in[5];
  const float* ad1w = (const float*)d_in[6];
  const float* We1  = (const float*)d_in[7];
  const float* ae1  = (const float*)d_in[8];
  const float* b1   = (const float*)d_in[9];
  const float* W2   = (const float*)d_in[10];
  const float* as2w = (const float*)d_in[11];
  const float* ad2w = (const float*)d_in[12];
  const float* We2  = (const float*)d_in[13];
  const float* ae2  = (const float*)d_in[14];
  const float* b2   = (const float*)d_in[15];
  const float* Wlin = (const float*)d_in[16];

  char* ws = (char*)d_ws;
  float* scal   = (float*)(ws + OFF_SCAL);
  int*   H      = (int*)  (ws + OFF_H);
  float* easum  = (float*)(ws + OFF_EAS);
  int*   part   = (int*)  (ws + OFF_PART);
  int*   ppref  = (int*)  (ws + OFF_PPREF);
  int*   bstart = (int*)  (ws + OFF_BST);
  int*   offs   = (int*)  (ws + OFF_OFFS);
  int2*  bpack  = (int2*) (ws + OFF_BPACK);
  unsigned int* edge2 = (unsigned int*)(ws + OFF_EDG);
  float* as1p   = (float*)(ws + OFF_AS1P);
  float* ad1p   = (float*)(ws + OFF_AD1P);
  __half* G16   = (__half*)(ws + OFF_G16);
  float* ad2p   = (float*)(ws + OFF_AD2P);
  unsigned short* h1q = (unsigned short*)(ws + OFF_H1Q);
  __half* x2h   = (__half*)(ws + OFF_X2H);
  float* outp   = (float*)d_out;

  k_init   <<<GRID_H1 + NBL, 320, 0, stream>>>(x, W1, as1w, ad1w, h1q, as1p, ad1p,
                                               dst, ea, H, easum);
  k_s1     <<<MC, 256, 0, stream>>>(H, part);
  k_s2p    <<<1, 512, 0, stream>>>(part, ppref, offs, bstart, easum, We1, ae1, We2, ae2, scal);
  k_s3     <<<MC, 256, 0, stream>>>(H, ppref, bstart);
  k_scat   <<<NBL, 256, 0, stream>>>(src, dst, ea, scal, H, bpack);
  k_final2 <<<NBK, 256, 0, stream>>>(bstart, bpack, offs, edge2);

  k_agg1   <<<N_NODES/8, 320, 0, stream>>>(offs, edge2, as1p, ad1p, scal, h1q, b1, x2h);
  k_h2     <<<N_NODES/4, 256, 0, stream>>>(x2h, W2, as2w, ad2w, G16, ad2p);
  k_agg2   <<<N_NODES/16, 256, 0, stream>>>(offs, edge2, G16, ad2p, scal, b2, Wlin, outp);
}

// Round 21
// 223.970 us; speedup vs baseline: 1.0202x; 1.0177x over previous
//
#include <hip/hip_runtime.h>
#include <hip/hip_fp16.h>
#include <math.h>

#define N_NODES 50000
#define N_EDGES 800000
#define E2 (N_EDGES + N_NODES)   // 850000
#define HEADS 5
#define C1 32
#define F1 160

// counting-sort CSR build (64-node buckets)
#define BSZ 64
#define NBK 782                  // 782*64 = 50048 >= N
#define NBL 128
#define CH  6641                 // 128*6641 >= E2
#define MTOT (NBK*NBL)           // 100096
#define MC  391                  // ceil(MTOT/256)
#define GRID_H1 (N_NODES/4)      // 12500 h1 blocks in k_init
#define CAP 1408                 // LDS staging cap per 64-node bucket

static constexpr size_t alignup(size_t x){ return (x + 255) & ~size_t(255); }
static constexpr size_t OFF_SCAL  = 0;                                           // 64 f
static constexpr size_t OFF_H     = alignup(OFF_SCAL + 64*4);                    // MTOT i
static constexpr size_t OFF_EAS   = alignup(OFF_H    + (size_t)MTOT*4);          // NBL f
static constexpr size_t OFF_PART  = alignup(OFF_EAS  + (size_t)NBL*4);           // MC i
static constexpr size_t OFF_PPREF = alignup(OFF_PART + (size_t)MC*4);            // MC i
static constexpr size_t OFF_BST   = alignup(OFF_PPREF+ (size_t)MC*4);            // NBK+1
static constexpr size_t OFF_OFFS  = alignup(OFF_BST  + (size_t)(NBK+1)*4);       // N+1
static constexpr size_t OFF_BPACK = alignup(OFF_OFFS + (size_t)(N_NODES+1)*4);   // E2 int2
static constexpr size_t OFF_EDG   = alignup(OFF_BPACK+ (size_t)E2*8);            // E2 u32
static constexpr size_t OFF_AS1P  = alignup(OFF_EDG  + (size_t)E2*4);            // N*8 f
static constexpr size_t OFF_AD1P  = alignup(OFF_AS1P + (size_t)N_NODES*8*4);
static constexpr size_t OFF_G16   = alignup(OFF_AD1P + (size_t)N_NODES*8*4);     // N*16 half
static constexpr size_t OFF_AD2P  = alignup(OFF_G16  + (size_t)N_NODES*16*2);    // N*8 f
static constexpr size_t OFF_H1Q   = alignup(OFF_AD2P + (size_t)N_NODES*8*4);     // N*160 fp8
static constexpr size_t OFF_X2H   = alignup(OFF_H1Q  + (size_t)N_NODES*F1);      // N*160 half

typedef float vf2 __attribute__((ext_vector_type(2)));
__device__ __forceinline__ float4 fp8x4_to_f32(unsigned int r){
  vf2 lo = __builtin_amdgcn_cvt_pk_f32_fp8((int)r, false);
  vf2 hi = __builtin_amdgcn_cvt_pk_f32_fp8((int)r, true);
  return make_float4(lo.x, lo.y, hi.x, hi.y);
}

// ---- fused: layer-1 projection (fp8 h1 out) + coarse histogram (last NBL blocks) ----
__global__ __launch_bounds__(320) void k_init(const float* __restrict__ x, const float* __restrict__ W1,
                       const float* __restrict__ as1w, const float* __restrict__ ad1w,
                       unsigned short* __restrict__ h1q, float* __restrict__ as1p, float* __restrict__ ad1p,
                       const int* __restrict__ dst, const float* __restrict__ ea,
                       int* __restrict__ H, float* __restrict__ easum){
  __shared__ float sW[5*F1];
  int t = threadIdx.x;
  if (blockIdx.x < GRID_H1){
    for (int k = t; k < 5*F1; k += 320) sW[k] = W1[k];
    __syncthreads();
    int nl = t / 80;
    int c  = t - nl*80;
    int n  = blockIdx.x*4 + nl;
    int c0 = 2*c;
    float hv0 = 0.f, hv1 = 0.f;
    #pragma unroll
    for (int f = 0; f < 5; f++){
      float xv = x[n*5 + f];
      hv0 += xv * sW[f*F1 + c0];
      hv1 += xv * sW[f*F1 + c0 + 1];
    }
    int pk = __builtin_amdgcn_cvt_pk_fp8_f32(hv0, hv1, 0, false);
    h1q[n*80 + c] = (unsigned short)(pk & 0xFFFF);
    float vs = hv0*as1w[c0] + hv1*as1w[c0+1];
    float vd = hv0*ad1w[c0] + hv1*ad1w[c0+1];
    #pragma unroll
    for (int m = 8; m >= 1; m >>= 1){
      vs += __shfl_xor(vs, m, 64);
      vd += __shfl_xor(vd, m, 64);
    }
    if ((c & 15) == 0){
      int h = c >> 4;
      as1p[n*8 + h] = vs;
      ad1p[n*8 + h] = vd;
    }
  } else {
    int* hist = (int*)sW;
    float* wsum = (float*)&hist[NBK + 1];
    for (int k = t; k < NBK; k += 320) hist[k] = 0;
    __syncthreads();
    int b = blockIdx.x - GRID_H1;
    int e0 = b*CH, e1 = min(e0 + CH, E2);
    float s = 0.f;
    for (int e = e0 + t; e < e1; e += 320){
      int d;
      if (e < N_EDGES){ d = dst[e]; s += ea[e]; }
      else d = e - N_EDGES;
      atomicAdd(&hist[d >> 6], 1);
    }
    #pragma unroll
    for (int m = 1; m < 64; m <<= 1) s += __shfl_xor(s, m, 64);
    if ((t & 63) == 0) wsum[t >> 6] = s;
    __syncthreads();
    for (int k = t; k < NBK; k += 320) H[(size_t)k*NBL + b] = hist[k];
    if (t == 0) easum[b] = wsum[0] + wsum[1] + wsum[2] + wsum[3] + wsum[4];
  }
}

// ---- parallel scan, stage 1 ----
__global__ void k_s1(const int* __restrict__ H, int* __restrict__ partial){
  int i = blockIdx.x*256 + threadIdx.x;
  int v = (i < MTOT) ? H[i] : 0;
  #pragma unroll
  for (int m = 1; m < 64; m <<= 1) v += __shfl_xor(v, m, 64);
  __shared__ int sh[4];
  if ((threadIdx.x & 63) == 0) sh[threadIdx.x >> 6] = v;
  __syncthreads();
  if (threadIdx.x == 0) partial[blockIdx.x] = sh[0] + sh[1] + sh[2] + sh[3];
}

// ---- stage 2: 512-thread scan of MC=391 partials + scalar prep ----
__global__ __launch_bounds__(512) void k_s2p(const int* __restrict__ partial, int* __restrict__ ppref,
                      int* __restrict__ offs, int* __restrict__ bstart,
                      const float* __restrict__ easum,
                      const float* __restrict__ We1, const float* __restrict__ ae1,
                      const float* __restrict__ We2, const float* __restrict__ ae2,
                      float* __restrict__ scal){
  __shared__ int sp[512];
  __shared__ float sh_ea[NBL];
  int t = threadIdx.x;
  if (t < NBL) sh_ea[t] = easum[t];
  if (t >= 448 && t < 448 + HEADS){
    int h = t - 448;
    float s = 0.f;
    for (int c = 0; c < C1; c++) s += We1[h*C1 + c] * ae1[h*C1 + c];
    scal[2 + h] = s;
    scal[7 + h] = We2[h] * ae2[h];
  }
  int v = (t < MC) ? partial[t] : 0;
  sp[t] = v;
  __syncthreads();
  if (t == 511){
    float es = 0.f;
    for (int i = 0; i < NBL; i++) es += sh_ea[i];
    scal[1] = es / (float)N_EDGES;
  }
  for (int off = 1; off < 512; off <<= 1){
    int u = (t >= off) ? sp[t - off] : 0;
    __syncthreads();
    sp[t] += u;
    __syncthreads();
  }
  if (t < MC) ppref[t] = sp[t] - v;
  if (t == 0){ offs[N_NODES] = E2; bstart[NBK] = E2; }
}

// ---- stage 3 ----
__global__ void k_s3(int* __restrict__ H, const int* __restrict__ ppref, int* __restrict__ bstart){
  __shared__ int sp[256];
  int b = blockIdx.x, t = threadIdx.x;
  int i = b*256 + t;
  int v = (i < MTOT) ? H[i] : 0;
  sp[t] = v;
  __syncthreads();
  for (int off = 1; off < 256; off <<= 1){
    int u = (t >= off) ? sp[t - off] : 0;
    __syncthreads();
    sp[t] += u;
    __syncthreads();
  }
  int P = ppref[b] + sp[t] - v;
  if (i < MTOT){
    H[i] = P;
    if (i % NBL == 0) bstart[i / NBL] = P;
  }
}

// ---- scatter into bucket-major packed records (8B/edge) ----
__global__ __launch_bounds__(256) void k_scat(const int* __restrict__ src, const int* __restrict__ dst,
                       const float* __restrict__ ea, const float* __restrict__ scal,
                       const int* __restrict__ H, int2* __restrict__ bpack){
  __shared__ int lofs[NBK];
  int b = blockIdx.x;
  for (int k = threadIdx.x; k < NBK; k += 256) lofs[k] = H[(size_t)k*NBL + b];
  __syncthreads();
  float mean = scal[1];
  int e0 = b*CH, e1 = min(e0 + CH, E2);
  for (int e = e0 + threadIdx.x; e < e1; e += 256){
    int d, s; float a;
    if (e < N_EDGES){ d = dst[e]; s = src[e]; a = ea[e]; }
    else { d = s = e - N_EDGES; a = mean; }
    int pos = atomicAdd(&lofs[d >> 6], 1);
    bpack[pos] = make_int2(s | ((d & 63) << 16), __float_as_int(a));
  }
}

// ---- per-bucket pure counting sort -> offs, edge2 (src|cea16) ----
__global__ __launch_bounds__(256) void k_final2(const int* __restrict__ bstart,
                        const int2* __restrict__ bpack,
                        int* __restrict__ offs, unsigned int* __restrict__ edge2){
  __shared__ int cnt[BSZ], cur[BSZ];
  __shared__ unsigned int s_edge[CAP];
  int k = blockIdx.x, t = threadIdx.x;
  int base = k*BSZ;
  if (t < BSZ) cnt[t] = 0;
  __syncthreads();
  int r0 = bstart[k], r1 = bstart[k + 1];
  int sz = r1 - r0;
  for (int j = r0 + t; j < r1; j += 256) atomicAdd(&cnt[(bpack[j].x >> 16) & 63], 1);
  __syncthreads();
  if (t == 0){
    int run = 0;
    for (int i = 0; i < BSZ; i++){ int c = cnt[i]; cnt[i] = run; cur[i] = run; run += c; }
  }
  __syncthreads();
  if (t < BSZ){
    int n = base + t;
    if (n < N_NODES) offs[n] = r0 + cnt[t];
  }
  if (sz <= CAP){
    for (int j = r0 + t; j < r1; j += 256){
      int2 v = bpack[j];
      int lp = atomicAdd(&cur[(v.x >> 16) & 63], 1);
      s_edge[lp] = (unsigned int)(v.x & 0xFFFF) |
                   ((unsigned int)__half_as_ushort(__float2half(__int_as_float(v.y))) << 16);
    }
    __syncthreads();
    for (int i = t; i < sz; i += 256) edge2[r0 + i] = s_edge[i];
  } else {
    for (int j = r0 + t; j < r1; j += 256){
      int2 v = bpack[j];
      int pos = r0 + atomicAdd(&cur[(v.x >> 16) & 63], 1);
      edge2[pos] = (unsigned int)(v.x & 0xFFFF) |
                   ((unsigned int)__half_as_ushort(__float2half(__int_as_float(v.y))) << 16);
    }
  }
}

// ---- layer 1 aggregate: inline softmax, 40 threads/node, fp8 quad gathers (R18-proven) ----
__global__ __launch_bounds__(320) void k_agg1(const int* __restrict__ offs,
                      const unsigned int* __restrict__ edge2,
                      const float* __restrict__ as1p, const float* __restrict__ ad1p,
                      const float* __restrict__ scal,
                      const unsigned short* __restrict__ h1q,
                      const float* __restrict__ b1, __half* __restrict__ x2h){
  int nl = threadIdx.x / 40;           // 8 nodes per block
  int c4 = threadIdx.x - nl*40;        // channel quad
  int n  = blockIdx.x*8 + nl;
  int h  = c4 >> 3;
  float wd  = scal[2 + h];
  float adn = ad1p[n*8 + h];
  const unsigned int* h1row = (const unsigned int*)h1q;
  int j0 = offs[n], j1 = offs[n + 1];
  float a0 = 0.f, a1 = 0.f, a2 = 0.f, a3 = 0.f, den = 0.f;
  int j = j0;
  for (; j + 7 < j1; j += 8){
    uint4 sa = *(const uint4*)(edge2 + j);
    uint4 sb = *(const uint4*)(edge2 + j + 4);
    unsigned int e0 = sa.x, e1 = sa.y, e2v = sa.z, e3 = sa.w;
    unsigned int e4 = sb.x, e5 = sb.y, e6 = sb.z, e7 = sb.w;
    int s0 = e0 & 0xFFFF, s1 = e1 & 0xFFFF, s2 = e2v & 0xFFFF, s3 = e3 & 0xFFFF;
    int s4 = e4 & 0xFFFF, s5 = e5 & 0xFFFF, s6 = e6 & 0xFFFF, s7 = e7 & 0xFFFF;
    unsigned int r0 = h1row[(size_t)s0*40 + c4];
    unsigned int r1 = h1row[(size_t)s1*40 + c4];
    unsigned int r2 = h1row[(size_t)s2*40 + c4];
    unsigned int r3 = h1row[(size_t)s3*40 + c4];
    unsigned int r4 = h1row[(size_t)s4*40 + c4];
    unsigned int r5 = h1row[(size_t)s5*40 + c4];
    unsigned int r6 = h1row[(size_t)s6*40 + c4];
    unsigned int r7 = h1row[(size_t)s7*40 + c4];
    float g0 = as1p[s0*8 + h], g1 = as1p[s1*8 + h];
    float g2 = as1p[s2*8 + h], g3 = as1p[s3*8 + h];
    float g4 = as1p[s4*8 + h], g5 = as1p[s5*8 + h];
    float g6 = as1p[s6*8 + h], g7 = as1p[s7*8 + h];
    float c0 = __half2float(__ushort_as_half((unsigned short)(e0 >> 16)));
    float c1 = __half2float(__ushort_as_half((unsigned short)(e1 >> 16)));
    float c2 = __half2float(__ushort_as_half((unsigned short)(e2v >> 16)));
    float c3 = __half2float(__ushort_as_half((unsigned short)(e3 >> 16)));
    float c4v = __half2float(__ushort_as_half((unsigned short)(e4 >> 16)));
    float c5v = __half2float(__ushort_as_half((unsigned short)(e5 >> 16)));
    float c6 = __half2float(__ushort_as_half((unsigned short)(e6 >> 16)));
    float c7 = __half2float(__ushort_as_half((unsigned short)(e7 >> 16)));
    float l0 = g0 + adn + c0*wd;  l0 = fminf(fmaxf(l0, 0.2f*l0), 10.f);
    float l1 = g1 + adn + c1*wd;  l1 = fminf(fmaxf(l1, 0.2f*l1), 10.f);
    float l2 = g2 + adn + c2*wd;  l2 = fminf(fmaxf(l2, 0.2f*l2), 10.f);
    float l3 = g3 + adn + c3*wd;  l3 = fminf(fmaxf(l3, 0.2f*l3), 10.f);
    float l4 = g4 + adn + c4v*wd; l4 = fminf(fmaxf(l4, 0.2f*l4), 10.f);
    float l5 = g5 + adn + c5v*wd; l5 = fminf(fmaxf(l5, 0.2f*l5), 10.f);
    float l6 = g6 + adn + c6*wd;  l6 = fminf(fmaxf(l6, 0.2f*l6), 10.f);
    float l7 = g7 + adn + c7*wd;  l7 = fminf(fmaxf(l7, 0.2f*l7), 10.f);
    float p0 = __expf(l0), p1 = __expf(l1), p2 = __expf(l2), p3 = __expf(l3);
    float p4 = __expf(l4), p5 = __expf(l5), p6 = __expf(l6), p7 = __expf(l7);
    den += p0 + p1 + p2 + p3 + p4 + p5 + p6 + p7;
    float4 f0 = fp8x4_to_f32(r0), f1 = fp8x4_to_f32(r1);
    float4 f2 = fp8x4_to_f32(r2), f3 = fp8x4_to_f32(r3);
    float4 f4 = fp8x4_to_f32(r4), f5 = fp8x4_to_f32(r5);
    float4 f6 = fp8x4_to_f32(r6), f7 = fp8x4_to_f32(r7);
    a0 += p0*f0.x; a1 += p0*f0.y; a2 += p0*f0.z; a3 += p0*f0.w;
    a0 += p1*f1.x; a1 += p1*f1.y; a2 += p1*f1.z; a3 += p1*f1.w;
    a0 += p2*f2.x; a1 += p2*f2.y; a2 += p2*f2.z; a3 += p2*f2.w;
    a0 += p3*f3.x; a1 += p3*f3.y; a2 += p3*f3.z; a3 += p3*f3.w;
    a0 += p4*f4.x; a1 += p4*f4.y; a2 += p4*f4.z; a3 += p4*f4.w;
    a0 += p5*f5.x; a1 += p5*f5.y; a2 += p5*f5.z; a3 += p5*f5.w;
    a0 += p6*f6.x; a1 += p6*f6.y; a2 += p6*f6.z; a3 += p6*f6.w;
    a0 += p7*f7.x; a1 += p7*f7.y; a2 += p7*f7.z; a3 += p7*f7.w;
  }
  for (; j < j1; ++j){
    unsigned int e = edge2[j];
    int s = e & 0xFFFF;
    float c = __half2float(__ushort_as_half((unsigned short)(e >> 16)));
    float g = as1p[s*8 + h];
    float lg = g + adn + c*wd;
    lg = fminf(fmaxf(lg, 0.2f*lg), 10.f);
    float p = __expf(lg);
    den += p;
    float4 f = fp8x4_to_f32(h1row[(size_t)s*40 + c4]);
    a0 += p*f.x; a1 += p*f.y; a2 += p*f.z; a3 += p*f.w;
  }
  float inv = 1.f / (den + 1e-16f);
  float4 bb = *(const float4*)(b1 + 4*c4);
  float v0 = fmaxf(a0*inv + bb.x, 0.f);
  float v1 = fmaxf(a1*inv + bb.y, 0.f);
  float v2 = fmaxf(a2*inv + bb.z, 0.f);
  float v3 = fmaxf(a3*inv + bb.w, 0.f);
  __half2 o0 = __floats2half2_rn(v0, v1);
  __half2 o1 = __floats2half2_rn(v2, v3);
  *(uint2*)(x2h + (size_t)n*F1 + 4*c4) =
      make_uint2(*(unsigned int*)&o0, *(unsigned int*)&o1);
}

// ---- layer 2: h2 = x2h@W2 -> packed fp16 G16 ([0..4]=h2, [5..9]=as2) + ad2p ----
__global__ __launch_bounds__(256) void k_h2(const __half* __restrict__ x2h, const float* __restrict__ W2,
                    const float* __restrict__ asw2, const float* __restrict__ adw2,
                    __half* __restrict__ G16, float* __restrict__ ad2p){
  __shared__ float sW[F1*HEADS];
  for (int k = threadIdx.x; k < F1*HEADS; k += 256) sW[k] = W2[k];
  __syncthreads();
  int w = threadIdx.x >> 6, l = threadIdx.x & 63;
  int n = blockIdx.x*4 + w;
  const __half2* x22 = (const __half2*)x2h;
  float acc[HEADS] = {0.f, 0.f, 0.f, 0.f, 0.f};
  for (int k2 = l; k2 < 80; k2 += 64){
    float2 f = __half22float2(x22[(size_t)n*80 + k2]);
    #pragma unroll
    for (int h = 0; h < HEADS; h++)
      acc[h] += f.x * sW[(2*k2)*HEADS + h] + f.y * sW[(2*k2+1)*HEADS + h];
  }
  #pragma unroll
  for (int m = 1; m < 64; m <<= 1){
    #pragma unroll
    for (int h = 0; h < HEADS; h++) acc[h] += __shfl_xor(acc[h], m, 64);
  }
  if (l == 0){
    #pragma unroll
    for (int h = 0; h < HEADS; h++){
      G16[(size_t)n*16 + h]     = __float2half(acc[h]);
      G16[(size_t)n*16 + 5 + h] = __float2half(acc[h] * asw2[h]);
      ad2p[n*8 + h]             = acc[h] * adw2[h];
    }
    #pragma unroll
    for (int z = 10; z < 16; z++) G16[(size_t)n*16 + z] = __float2half(0.f);
  }
}

// ---- layer 2: 16-lane-group-per-node softmax aggregate + mean + linear + sigmoid ----
__global__ __launch_bounds__(256) void k_agg2(const int* __restrict__ offs,
                      const unsigned int* __restrict__ edge2,
                      const __half* __restrict__ G16, const float* __restrict__ ad2p,
                      const float* __restrict__ scal,
                      const float* __restrict__ b2, const float* __restrict__ Wlin,
                      float* __restrict__ out){
  int grp = threadIdx.x >> 4;
  int l16 = threadIdx.x & 15;
  int n = blockIdx.x*16 + grp;
  float adn[HEADS], wd[HEADS];
  #pragma unroll
  for (int h = 0; h < HEADS; h++){ adn[h] = ad2p[n*8 + h]; wd[h] = scal[7 + h]; }
  int j0 = offs[n], j1 = offs[n + 1];

  float den[HEADS] = {0,0,0,0,0};
  float ac[HEADS]  = {0,0,0,0,0};
  for (int j = j0 + l16; j < j1; j += 16){
    unsigned int e = edge2[j];
    int s = e & 0xFFFF;
    float c = __half2float(__ushort_as_half((unsigned short)(e >> 16)));
    const __half* gs = G16 + (size_t)s*16;
    union { uint4 u; __half2 h[4]; } U; U.u = *(const uint4*)gs;
    union { uint2 u; __half2 h[2]; } V; V.u = *(const uint2*)(gs + 8);
    float2 p01 = __half22float2(U.h[0]);
    float2 p23 = __half22float2(U.h[1]);
    float2 p45 = __half22float2(U.h[2]);
    float2 p67 = __half22float2(U.h[3]);
    float2 p89 = __half22float2(V.h[0]);
    float hv[HEADS] = {p01.x, p01.y, p23.x, p23.y, p45.x};
    float av[HEADS] = {p45.y, p67.x, p67.y, p89.x, p89.y};
    #pragma unroll
    for (int h = 0; h < HEADS; h++){
      float lg = av[h] + adn[h] + c*wd[h];
      lg = fmaxf(lg, 0.2f*lg);
      lg = fminf(lg, 50.f);
      float p = __expf(lg);
      den[h] += p;
      ac[h]  += p * hv[h];
    }
  }
  #pragma unroll
  for (int m = 1; m < 16; m <<= 1){
    #pragma unroll
    for (int h = 0; h < HEADS; h++){
      den[h] += __shfl_xor(den[h], m, 16);
      ac[h]  += __shfl_xor(ac[h], m, 16);
    }
  }
  if (l16 == 0){
    float v = 0.f;
    #pragma unroll
    for (int h = 0; h < HEADS; h++) v += ac[h] / (den[h] + 1e-16f);
    v = v * (1.f/HEADS) + b2[0];
    v *= Wlin[0];
    out[n] = 1.f / (1.f + __expf(-v));
  }
}

extern "C" void kernel_launch(void* const* d_in, const int* in_sizes, int n_in,
                              void* d_out, int out_size, void* d_ws, size_t ws_size,
                              hipStream_t stream) {
  const float* x    = (const float*)d_in[0];
  const float* ea   = (const float*)d_in[1];
  const int*   src  = (const int*)d_in[2];
  const int*   dst  = (const int*)d_in[3];
  const float* W1   = (const float*)d_in[4];
  const float* as1w = (const float*)d_in[5];
  const float* ad1w = (const float*)d_in[6];
  const float* We1  = (const float*)d_in[7];
  const float* ae1  = (const float*)d_in[8];
  const float* b1   = (const float*)d_in[9];
  const float* W2   = (const float*)d_in[10];
  const float* as2w = (const float*)d_in[11];
  const float* ad2w = (const float*)d_in[12];
  const float* We2  = (const float*)d_in[13];
  const float* ae2  = (const float*)d_in[14];
  const float* b2   = (const float*)d_in[15];
  const float* Wlin = (const float*)d_in[16];

  char* ws = (char*)d_ws;
  float* scal   = (float*)(ws + OFF_SCAL);
  int*   H      = (int*)  (ws + OFF_H);
  float* easum  = (float*)(ws + OFF_EAS);
  int*   part   = (int*)  (ws + OFF_PART);
  int*   ppref  = (int*)  (ws + OFF_PPREF);
  int*   bstart = (int*)  (ws + OFF_BST);
  int*   offs   = (int*)  (ws + OFF_OFFS);
  int2*  bpack  = (int2*) (ws + OFF_BPACK);
  unsigned int* edge2 = (unsigned int*)(ws + OFF_EDG);
  float* as1p   = (float*)(ws + OFF_AS1P);
  float* ad1p   = (float*)(ws + OFF_AD1P);
  __half* G16   = (__half*)(ws + OFF_G16);
  float* ad2p   = (float*)(ws + OFF_AD2P);
  unsigned short* h1q = (unsigned short*)(ws + OFF_H1Q);
  __half* x2h   = (__half*)(ws + OFF_X2H);
  float* outp   = (float*)d_out;

  k_init   <<<GRID_H1 + NBL, 320, 0, stream>>>(x, W1, as1w, ad1w, h1q, as1p, ad1p,
                                               dst, ea, H, easum);
  k_s1     <<<MC, 256, 0, stream>>>(H, part);
  k_s2p    <<<1, 512, 0, stream>>>(part, ppref, offs, bstart, easum, We1, ae1, We2, ae2, scal);
  k_s3     <<<MC, 256, 0, stream>>>(H, ppref, bstart);
  k_scat   <<<NBL, 256, 0, stream>>>(src, dst, ea, scal, H, bpack);
  k_final2 <<<NBK, 256, 0, stream>>>(bstart, bpack, offs, edge2);

  k_agg1   <<<N_NODES/8, 320, 0, stream>>>(offs, edge2, as1p, ad1p, scal, h1q, b1, x2h);
  k_h2     <<<N_NODES/4, 256, 0, stream>>>(x2h, W2, as2w, ad2w, G16, ad2p);
  k_agg2   <<<N_NODES/16, 256, 0, stream>>>(offs, edge2, G16, ad2p, scal, b2, Wlin, outp);
}